// Round 6
// baseline (9536.136 us; speedup 1.0000x reference)
//
#include <hip/hip_runtime.h>
#include <math.h>

// ---------------------------------------------------------------------------
// Sizes (fixed by the problem)
//   input_context  [512][768]   output_context [1024][768]
//   fw_wih [1536][768] fw_whh [1536][512] fw_bih/bhh [1536]
//   bw_wih [1536][768] (whh unused: bwd_hs[-1] = one step from h0=0)
//   dec_wih [3072][768] dec_whh [3072][1024] dec_bih/bhh [3072]
//   W_pred [1024][28996]   out [1024][28996] fp32
// ---------------------------------------------------------------------------

typedef unsigned long long u64;
typedef unsigned short ushort_t;
typedef __attribute__((ext_vector_type(8))) short short8;   // 8 bf16 (4 VGPR)
typedef __attribute__((ext_vector_type(4))) float f32x4;

#define NWG 64
#define NT 512
#define NV 28996

__device__ __forceinline__ float sigmoidf_(float x) {
  return 1.0f / (1.0f + __expf(-x));
}
__device__ __forceinline__ float tanhf_(float x) {
  const float xx = fminf(fmaxf(x, -15.0f), 15.0f);
  const float e = __expf(2.0f * xx);
  return (e - 1.0f) / (e + 1.0f);
}
__device__ __forceinline__ ushort_t f2bf(float f) {
  union { float f; unsigned u; } c; c.f = f;
  unsigned u = c.u;
  u += 0x7fffu + ((u >> 16) & 1u);  // RNE
  return (ushort_t)(u >> 16);
}

__device__ __forceinline__ float wave_reduce_sum(float v) {
#pragma unroll
  for (int s = 1; s < 64; s <<= 1) v += __shfl_xor(v, s, 64);
  return v;
}

// Loop-end VGPR pin: "+v" def at the END of each iteration makes the weight
// vector loop-carried in a register (next iteration's FMAs consume the asm's
// def) -> rematerialization-from-memory is no longer legal.
__device__ __forceinline__ void pinv(f32x4& v) {
  asm volatile("" : "+v"(v));
}

// (tag, h) fused in one 8-byte word: single relaxed agent-scope atomic store
// publishes value + readiness together. Tags are the sole sync authority.
__device__ __forceinline__ u64 pack_ht(float h, unsigned tag) {
  union { float f; unsigned u; } c; c.f = h;
  return ((u64)tag << 32) | (u64)c.u;
}
__device__ __forceinline__ float pk_h(u64 v) {
  union { unsigned u; float f; } c; c.u = (unsigned)v; return c.f;
}
__device__ __forceinline__ void astore(u64* p, u64 v) {
  __hip_atomic_store(p, v, __ATOMIC_RELAXED, __HIP_MEMORY_SCOPE_AGENT);
}
__device__ __forceinline__ u64 aload(const u64* p) {
  return __hip_atomic_load((u64*)p, __ATOMIC_RELAXED, __HIP_MEMORY_SCOPE_AGENT);
}

// ---------------------------------------------------------------------------
// Persistent recurrence kernel. 64 wgs x 512 threads.
// REPLICATED PUBLISH / PRIVATE POLL:
//   fwrep  u64[64 consumers][2 parity][512 units]
//   decrep u64[64 consumers][2 parity][1024 units]
// Producer wave w of wg g: after the butterfly reduce ALL lanes hold the
// sums; every lane computes hnew redundantly and lane c stores (tag,h) into
// consumer c's private mailbox -> one scatter-store instruction replicates a
// unit to all 64 consumers. Consumers poll ONLY their own region: no cache
// line is ever read by more than one wg -> no coherence-point serialization.
// Publish needs no barrier (no LDS staging) -> one __syncthreads per step.
// Depth-2 ping-pong safety: replica slot (c,u,parity) written with tag t+3
// only after its producer finished step t+2, which required consumer c's
// t+2 publication, which required c's read of (u, t+1) to have completed.
// ---------------------------------------------------------------------------
__global__ __launch_bounds__(NT, 1) void recur_kernel(
    const float* __restrict__ gxfw,    // [512][1536]
    const float* __restrict__ gxdec,   // [1024][3072]
    const float* __restrict__ gxbw,    // [1536]
    const float* __restrict__ whh_fw,  // [1536][512]
    const float* __restrict__ bhh_fw,  // [1536]
    const float* __restrict__ whh_dec, // [3072][1024]
    const float* __restrict__ bhh_dec, // [3072]
    const float* __restrict__ bhh_bw,  // [1536]
    u64* fwrep,                        // zeroed: (h=0, tag=0)
    u64* decrep,                       // zeroed
    float* __restrict__ dec_hs,        // [1024][1024] f32 (fallback GEMM)
    ushort_t* __restrict__ dec_hs_bf,  // [1024][1024] bf16 (MFMA GEMM)
    int do_bf16)
{
  __shared__ float Hs[2048];  // ping-pong: fw 2x512 (low half), dec 2x1024
  const int tid = threadIdx.x;
  const int wg = blockIdx.x;
  const int wave = tid >> 6;
  const int lane = tid & 63;

  // backward "encoder" = one GRU cell on input row 511 from h0=0 (gh = bhh).
  // Replicated to all 64 consumers' parity-0 slots 512..1023, tag 512.
  if (wg == 0) {
    const int j = tid;  // NT == 512 == HIDDEN
    const float r = sigmoidf_(gxbw[j] + bhh_bw[j]);
    const float z = sigmoidf_(gxbw[512 + j] + bhh_bw[512 + j]);
    const float n = tanhf_(gxbw[1024 + j] + r * bhh_bw[1024 + j]);
    const u64 pv = pack_ht((1.0f - z) * n, 512u);
    for (int c = 0; c < 64; ++c)  // coalesced 4KB store per consumer
      astore(decrep + (c << 11) + 512 + j, pv);
  }

  // ---------------- forward encoder: 512 steps ----------------
  {
    const int u = (wg << 3) + wave;  // 0..511, one unit per wave
    const float br = bhh_fw[u], bz = bhh_fw[512 + u], bn = bhh_fw[1024 + u];
    f32x4 wr[3][2];  // 3 gate rows x 8 f32 per lane
#pragma unroll
    for (int g = 0; g < 3; ++g) {
      const float* w = whh_fw + (size_t)(g * 512 + u) * 512;
#pragma unroll
      for (int i = 0; i < 2; ++i)
        wr[g][i] = *(const f32x4*)&w[(i << 8) + (lane << 2)];
    }
    for (int t = 0; t < 512; ++t) {
      const u64* src = fwrep + (wg << 10) + ((t & 1) << 9);  // private region
      float* hs = Hs + ((t & 1) << 9);
      // gx loads issued before poll/barrier (latency hidden under the wait)
      const float* gx = gxfw + (size_t)t * 1536;
      const float g0 = gx[u], g1 = gx[512 + u], g2 = gx[1024 + u];
      if (wave == 0) {  // masked incremental poll of PRIVATE lines
        u64 v[8];
        unsigned need = 0xFFu;
        for (;;) {
          unsigned nnew = 0;
#pragma unroll
          for (int j = 0; j < 8; ++j) {
            if ((need >> j) & 1u) {
              v[j] = aload(src + (j << 6) + lane);
              if ((unsigned)(v[j] >> 32) < (unsigned)t) nnew |= 1u << j;
            }
          }
          need = nnew;
          if (__all(need == 0)) break;
        }
#pragma unroll
        for (int j = 0; j < 8; ++j) hs[(j << 6) + lane] = pk_h(v[j]);
      }
      __syncthreads();  // the ONLY barrier per fw step
      const f32x4 ha = *(const f32x4*)&hs[lane << 2];
      const f32x4 hb = *(const f32x4*)&hs[256 + (lane << 2)];
      float p0 = wr[0][0][0] * ha[0] + wr[0][0][1] * ha[1] +
                 wr[0][0][2] * ha[2] + wr[0][0][3] * ha[3] +
                 wr[0][1][0] * hb[0] + wr[0][1][1] * hb[1] +
                 wr[0][1][2] * hb[2] + wr[0][1][3] * hb[3];
      float p1 = wr[1][0][0] * ha[0] + wr[1][0][1] * ha[1] +
                 wr[1][0][2] * ha[2] + wr[1][0][3] * ha[3] +
                 wr[1][1][0] * hb[0] + wr[1][1][1] * hb[1] +
                 wr[1][1][2] * hb[2] + wr[1][1][3] * hb[3];
      float p2 = wr[2][0][0] * ha[0] + wr[2][0][1] * ha[1] +
                 wr[2][0][2] * ha[2] + wr[2][0][3] * ha[3] +
                 wr[2][1][0] * hb[0] + wr[2][1][1] * hb[1] +
                 wr[2][1][2] * hb[2] + wr[2][1][3] * hb[3];
      p0 = wave_reduce_sum(p0);
      p1 = wave_reduce_sum(p1);
      p2 = wave_reduce_sum(p2);
      // every lane computes hnew; lane c publishes to consumer c (one
      // scatter-store instruction replicates this unit to all 64 wgs)
      const float hold = hs[u];
      const float r = sigmoidf_(g0 + p0 + br);
      const float z = sigmoidf_(g1 + p1 + bz);
      const float n = tanhf_(g2 + r * (p2 + bn));
      const float hnew = (1.0f - z) * n + z * hold;
      u64* dst = (t < 511)
                     ? fwrep + (lane << 10) + (((t + 1) & 1) << 9) + (wg << 3) + wave
                     : decrep + (lane << 11) + (wg << 3) + wave;  // parity 0
      astore(dst, pack_ht(hnew, (unsigned)(t + 1)));
#pragma unroll
      for (int g = 0; g < 3; ++g)
#pragma unroll
        for (int i = 0; i < 2; ++i) pinv(wr[g][i]);
    }
  }
  __syncthreads();  // LDS region handoff fw -> dec

  // ---------------- decoder: 1024 steps ----------------
  {
    const int u0 = (wg << 4) + (wave << 1);  // 2 units per wave
    float bb0[2], bb1[2], bb2[2];
    f32x4 wr[2][3][4];  // 2 units x 3 gates x 16 f32 per lane
#pragma unroll
    for (int uu = 0; uu < 2; ++uu) {
      bb0[uu] = bhh_dec[u0 + uu];
      bb1[uu] = bhh_dec[1024 + u0 + uu];
      bb2[uu] = bhh_dec[2048 + u0 + uu];
#pragma unroll
      for (int g = 0; g < 3; ++g) {
        const float* w = whh_dec + (size_t)(g * 1024 + u0 + uu) * 1024;
#pragma unroll
        for (int i = 0; i < 4; ++i)
          wr[uu][g][i] = *(const f32x4*)&w[(i << 8) + (lane << 2)];
      }
    }
    for (int td = 0; td < 1024; ++td) {
      const int t = 512 + td;  // global tag
      const u64* src = decrep + (wg << 11) + ((t & 1) << 10);  // private
      float* hs = Hs + ((t & 1) << 10);
      const float* gx = gxdec + (size_t)td * 3072;
      float ga[2], gb[2], gc[2];
#pragma unroll
      for (int uu = 0; uu < 2; ++uu) {
        ga[uu] = gx[u0 + uu];
        gb[uu] = gx[1024 + u0 + uu];
        gc[uu] = gx[2048 + u0 + uu];
      }
      if (wave < 2) {  // two polling waves, 8 private slot-groups each
        const u64* s2 = src + (wave << 9);
        float* h2 = hs + (wave << 9);
        u64 v[8];
        unsigned need = 0xFFu;
        for (;;) {
          unsigned nnew = 0;
#pragma unroll
          for (int j = 0; j < 8; ++j) {
            if ((need >> j) & 1u) {
              v[j] = aload(s2 + (j << 6) + lane);
              if ((unsigned)(v[j] >> 32) < (unsigned)t) nnew |= 1u << j;
            }
          }
          need = nnew;
          if (__all(need == 0)) break;
        }
#pragma unroll
        for (int j = 0; j < 8; ++j) h2[(j << 6) + lane] = pk_h(v[j]);
      }
      __syncthreads();  // the ONLY barrier per dec step
      f32x4 h4[4];
#pragma unroll
      for (int i = 0; i < 4; ++i)
        h4[i] = *(const f32x4*)&hs[(i << 8) + (lane << 2)];
      float hn[2];
#pragma unroll
      for (int uu = 0; uu < 2; ++uu) {
        float p0 = 0.f, p1 = 0.f, p2 = 0.f;
#pragma unroll
        for (int i = 0; i < 4; ++i) {
          p0 += wr[uu][0][i][0] * h4[i][0] + wr[uu][0][i][1] * h4[i][1] +
                wr[uu][0][i][2] * h4[i][2] + wr[uu][0][i][3] * h4[i][3];
          p1 += wr[uu][1][i][0] * h4[i][0] + wr[uu][1][i][1] * h4[i][1] +
                wr[uu][1][i][2] * h4[i][2] + wr[uu][1][i][3] * h4[i][3];
          p2 += wr[uu][2][i][0] * h4[i][0] + wr[uu][2][i][1] * h4[i][1] +
                wr[uu][2][i][2] * h4[i][2] + wr[uu][2][i][3] * h4[i][3];
        }
        p0 = wave_reduce_sum(p0);
        p1 = wave_reduce_sum(p1);
        p2 = wave_reduce_sum(p2);
        const int u = u0 + uu;
        const float hold = hs[u];
        const float r = sigmoidf_(ga[uu] + p0 + bb0[uu]);
        const float z = sigmoidf_(gb[uu] + p1 + bb1[uu]);
        const float n = tanhf_(gc[uu] + r * (p2 + bb2[uu]));
        hn[uu] = (1.0f - z) * n + z * hold;
      }
      // replicate both units to all 64 consumers: lane c -> consumer c,
      // two adjacent 8B atomic stores (same line)
      u64* dst = decrep + (lane << 11) + (((t + 1) & 1) << 10) + (wg << 4) +
                 (wave << 1);
      astore(dst, pack_ht(hn[0], (unsigned)(t + 1)));
      astore(dst + 1, pack_ht(hn[1], (unsigned)(t + 1)));
      if (lane == 0) {  // output row (off critical path)
        if (do_bf16) {
          const unsigned pk =
              (unsigned)f2bf(hn[0]) | ((unsigned)f2bf(hn[1]) << 16);
          *(unsigned*)&dec_hs_bf[(size_t)td * 1024 + u0] = pk;
        } else {
          dec_hs[(size_t)td * 1024 + u0] = hn[0];
          dec_hs[(size_t)td * 1024 + u0 + 1] = hn[1];
        }
      }
#pragma unroll
      for (int uu = 0; uu < 2; ++uu)
#pragma unroll
        for (int g = 0; g < 3; ++g)
#pragma unroll
          for (int i = 0; i < 4; ++i) pinv(wr[uu][g][i]);
    }
  }
}

// ---------------------------------------------------------------------------
// W_pred [1024][28996] f32  ->  Wt [28996][1024] bf16 (k-contiguous rows).
// 64x64 LDS-tiled transpose, coalesced on both sides.
// ---------------------------------------------------------------------------
__global__ __launch_bounds__(256) void wt_transpose(
    const float* __restrict__ W, ushort_t* __restrict__ Wt) {
  __shared__ float T[64][65];
  const int tid = threadIdx.x;
  const int n0 = blockIdx.x * 64;
  const int k0 = blockIdx.y * 64;
  const int nloc = tid & 63;
  const int q = tid >> 6;  // 0..3
  const bool nok = (n0 + nloc) < NV;
#pragma unroll
  for (int r = 0; r < 16; ++r) {
    const int kloc = q + r * 4;
    T[kloc][nloc] = nok ? W[(size_t)(k0 + kloc) * NV + n0 + nloc] : 0.f;
  }
  __syncthreads();
  const int kloc2 = tid & 63;
#pragma unroll
  for (int w = 0; w < 16; ++w) {
    const int nloc2 = q + w * 4;
    if (n0 + nloc2 < NV)
      Wt[(size_t)(n0 + nloc2) * 1024 + k0 + kloc2] = f2bf(T[kloc2][nloc2]);
  }
}

// ---------------------------------------------------------------------------
// bf16 MFMA vocab GEMM: out[1024][28996] = dec_hs_bf[1024][1024] x W_pred,
// with B pre-transposed as Wt[28996][1024] bf16 (k-contiguous rows).
// 128x128 tile, BK=64, 512 threads = 8 waves (4M x 2N), 16x16x32 MFMA.
// ---------------------------------------------------------------------------
__global__ __launch_bounds__(512) void gemm_vocab_bf16(
    const ushort_t* __restrict__ A,   // [1024][1024] bf16
    const ushort_t* __restrict__ Bt,  // [28996][1024] bf16
    float* __restrict__ C) {          // [1024][28996] f32
  __shared__ short As[128 * 72];
  __shared__ short Bs[128 * 72];
  const int tid = threadIdx.x;
  const int lane = tid & 63;
  const int wid = tid >> 6;
  const int wm = wid >> 1;   // 0..3
  const int wn = wid & 1;    // 0..1
  const int n0 = blockIdx.x * 128;
  const int m0 = blockIdx.y * 128;

  const int frow = tid >> 2;          // 0..127 (fill row)
  const int fko = (tid & 3) << 4;     // k offset 0/16/32/48
  const bool bok = (n0 + frow) < NV;
  const uint4 zz = make_uint4(0, 0, 0, 0);

  f32x4 acc[2][4];
#pragma unroll
  for (int i = 0; i < 2; ++i)
#pragma unroll
    for (int j = 0; j < 4; ++j) acc[i][j] = (f32x4){0.f, 0.f, 0.f, 0.f};

  for (int k0 = 0; k0 < 1024; k0 += 64) {
    {  // A fill: 128 rows x 64 k bf16, 32B per thread
      const uint4* s = (const uint4*)(A + (size_t)(m0 + frow) * 1024 + k0 + fko);
      uint4* d = (uint4*)&As[frow * 72 + fko];
      d[0] = s[0];
      d[1] = s[1];
    }
    {  // B fill from Wt rows (n-major, k-contiguous)
      uint4 v0 = zz, v1 = zz;
      if (bok) {
        const uint4* s =
            (const uint4*)(Bt + (size_t)(n0 + frow) * 1024 + k0 + fko);
        v0 = s[0];
        v1 = s[1];
      }
      uint4* d = (uint4*)&Bs[frow * 72 + fko];
      d[0] = v0;
      d[1] = v1;
    }
    __syncthreads();
#pragma unroll
    for (int ks = 0; ks < 64; ks += 32) {
      short8 a[2], b[4];
#pragma unroll
      for (int fm = 0; fm < 2; ++fm)
        a[fm] = *(const short8*)&As[(wm * 32 + fm * 16 + (lane & 15)) * 72 +
                                    ks + ((lane >> 4) << 3)];
#pragma unroll
      for (int fn = 0; fn < 4; ++fn)
        b[fn] = *(const short8*)&Bs[(wn * 64 + fn * 16 + (lane & 15)) * 72 +
                                    ks + ((lane >> 4) << 3)];
#pragma unroll
      for (int fm = 0; fm < 2; ++fm)
#pragma unroll
        for (int fn = 0; fn < 4; ++fn)
          acc[fm][fn] = __builtin_amdgcn_mfma_f32_16x16x32_bf16(
              a[fm], b[fn], acc[fm][fn], 0, 0, 0);
    }
    __syncthreads();
  }

#pragma unroll
  for (int fm = 0; fm < 2; ++fm) {
#pragma unroll
    for (int fn = 0; fn < 4; ++fn) {
      const int col = n0 + wn * 64 + fn * 16 + (lane & 15);
      if (col < NV) {
        const int rbase = m0 + wm * 32 + fm * 16 + ((lane >> 4) << 2);
#pragma unroll
        for (int r = 0; r < 4; ++r)
          C[(size_t)(rbase + r) * NV + col] = acc[fm][fn][r];
      }
    }
  }
}

// ---------------------------------------------------------------------------
// fp32 GEMM, 128x128 tile, BK=16, 256 threads, 8x8 microtile.
//   BT=1: C[M,N] = Amap[M,K] * B[N,K]^T + bias   (input projections)
//   BT=0: C[M,N] = A[M,K]   * B[K,N]   (+bias)   (vocab fallback)
// rowmode: 0 identity, 1 decoder shift (row m -> max(m-1,0)), 2 fixed row.
// ---------------------------------------------------------------------------
#define GBM 128
#define GBN 128
#define GBK 16
#define GLDS 132

template <int BT>
__global__ __launch_bounds__(256) void gemm128(
    const float* __restrict__ A, const float* __restrict__ B,
    const float* __restrict__ bias, float* __restrict__ C, int M, int N, int K,
    int rowmode, int fixedrow) {
  __shared__ float As[GBK][GLDS];
  __shared__ float Bs[GBK][GLDS];
  const int tid = threadIdx.x;
  const int n0 = blockIdx.x * GBN;
  const int m0 = blockIdx.y * GBM;
  const int tx = tid & 15;
  const int ty = tid >> 4;
  float acc[8][8];
#pragma unroll
  for (int i = 0; i < 8; ++i)
#pragma unroll
    for (int j = 0; j < 8; ++j) acc[i][j] = 0.f;

  const int fl = tid >> 1;
  const int fk = (tid & 1) << 3;
  const int am = m0 + fl;
  int asrow = am;
  if (rowmode == 1) asrow = (am == 0) ? 0 : am - 1;
  else if (rowmode == 2) asrow = fixedrow;
  const bool aok = (am < M);
  const bool nfull = (n0 + GBN <= N);

  for (int k0 = 0; k0 < K; k0 += GBK) {
    {
      float4 v0 = make_float4(0.f, 0.f, 0.f, 0.f), v1 = v0;
      if (aok) {
        const float* p = A + (size_t)asrow * K + k0 + fk;
        v0 = *(const float4*)p;
        v1 = *(const float4*)(p + 4);
      }
      As[fk + 0][fl] = v0.x; As[fk + 1][fl] = v0.y;
      As[fk + 2][fl] = v0.z; As[fk + 3][fl] = v0.w;
      As[fk + 4][fl] = v1.x; As[fk + 5][fl] = v1.y;
      As[fk + 6][fl] = v1.z; As[fk + 7][fl] = v1.w;
    }
    if (BT) {
      const int bn = n0 + fl;
      float4 v0 = make_float4(0.f, 0.f, 0.f, 0.f), v1 = v0;
      if (bn < N) {
        const float* p = B + (size_t)bn * K + k0 + fk;
        v0 = *(const float4*)p;
        v1 = *(const float4*)(p + 4);
      }
      Bs[fk + 0][fl] = v0.x; Bs[fk + 1][fl] = v0.y;
      Bs[fk + 2][fl] = v0.z; Bs[fk + 3][fl] = v0.w;
      Bs[fk + 4][fl] = v1.x; Bs[fk + 5][fl] = v1.y;
      Bs[fk + 6][fl] = v1.z; Bs[fk + 7][fl] = v1.w;
    } else {
      const int kl = tid >> 4;
      const int nq = (tid & 15) << 3;
      const float* p = B + (size_t)(k0 + kl) * N + n0 + nq;
      if (nfull) {
        *(float4*)&Bs[kl][nq] = *(const float4*)p;
        *(float4*)&Bs[kl][nq + 4] = *(const float4*)(p + 4);
      } else {
#pragma unroll
        for (int j = 0; j < 8; ++j)
          Bs[kl][nq + j] = (n0 + nq + j < N) ? p[j] : 0.f;
      }
    }
    __syncthreads();
#pragma unroll
    for (int k = 0; k < GBK; ++k) {
      const float4 a0 = *(const float4*)&As[k][ty << 3];
      const float4 a1 = *(const float4*)&As[k][(ty << 3) + 4];
      const float4 b0 = *(const float4*)&Bs[k][tx << 3];
      const float4 b1 = *(const float4*)&Bs[k][(tx << 3) + 4];
      const float av[8] = {a0.x, a0.y, a0.z, a0.w, a1.x, a1.y, a1.z, a1.w};
      const float bv[8] = {b0.x, b0.y, b0.z, b0.w, b1.x, b1.y, b1.z, b1.w};
#pragma unroll
      for (int i = 0; i < 8; ++i)
#pragma unroll
        for (int j = 0; j < 8; ++j) acc[i][j] += av[i] * bv[j];
    }
    __syncthreads();
  }

  const int mb = m0 + (ty << 3);
  const int nb = n0 + (tx << 3);
#pragma unroll
  for (int i = 0; i < 8; ++i) {
    const int m = mb + i;
    if (m >= M) continue;
    float o[8];
#pragma unroll
    for (int j = 0; j < 8; ++j) o[j] = acc[i][j];
    if (nfull) {
      if (bias) {
#pragma unroll
        for (int j = 0; j < 8; ++j) o[j] += bias[nb + j];
      }
      *(float4*)&C[(size_t)m * N + nb] = make_float4(o[0], o[1], o[2], o[3]);
      *(float4*)&C[(size_t)m * N + nb + 4] = make_float4(o[4], o[5], o[6], o[7]);
    } else {
#pragma unroll
      for (int j = 0; j < 8; ++j) {
        const int n = nb + j;
        if (n < N) C[(size_t)m * N + n] = o[j] + (bias ? bias[n] : 0.f);
      }
    }
  }
}

// ---------------------------------------------------------------------------
// Workspace layout (byte offsets):
//   0         fwrep  u64[64][2][512]   = 512 KB (zeroed each launch)
//   524288    decrep u64[64][2][1024]  = 1 MB   (zeroed each launch)
//   1572864   gxbw   f32[1536]
//   1579008   gxfw   f32[512*1536]
//   4724736   gxdec  f32[1024*3072]
//   17307648  dec_hs f32[1024*1024]  UNION  dec_hs_bf16 u16[1024*1024]
//   21501952  Wt bf16 u16[28996*1024]  -> end 80885760 (~80.9 MB)
// bf16 path requires ws_size >= 80885760; else fp32 fallback.
// ---------------------------------------------------------------------------
extern "C" void kernel_launch(void* const* d_in, const int* in_sizes, int n_in,
                              void* d_out, int out_size, void* d_ws,
                              size_t ws_size, hipStream_t stream) {
  (void)in_sizes; (void)n_in; (void)out_size;
  const float* input_context  = (const float*)d_in[0];
  const float* output_context = (const float*)d_in[1];
  const float* fw_wih = (const float*)d_in[2];
  const float* fw_whh = (const float*)d_in[3];
  const float* fw_bih = (const float*)d_in[4];
  const float* fw_bhh = (const float*)d_in[5];
  const float* bw_wih = (const float*)d_in[6];
  const float* bw_bih = (const float*)d_in[8];
  const float* bw_bhh = (const float*)d_in[9];
  const float* dec_wih = (const float*)d_in[10];
  const float* dec_whh = (const float*)d_in[11];
  const float* dec_bih = (const float*)d_in[12];
  const float* dec_bhh = (const float*)d_in[13];
  const float* W_pred  = (const float*)d_in[14];
  float* out = (float*)d_out;

  char* wsb = (char*)d_ws;
  u64* fwrep   = (u64*)wsb;
  u64* decrep  = (u64*)(wsb + 524288);
  float* gxbw  = (float*)(wsb + 1572864);
  float* gxfw  = (float*)(wsb + 1579008);
  float* gxdec = (float*)(wsb + 4724736);
  float* dec_hs = (float*)(wsb + 17307648);
  ushort_t* dec_hs_bf = (ushort_t*)(wsb + 17307648);  // union with dec_hs
  ushort_t* Wt = (ushort_t*)(wsb + 21501952);
  const int do_bf16 = (ws_size >= 80885760u) ? 1 : 0;

  // zero the replica mailboxes: tag=0 (= ready only for t=0), h0=0
  hipMemsetAsync(d_ws, 0, 1572864, stream);

  const dim3 blk(256);
  gemm128<1><<<dim3(12, 4), blk, 0, stream>>>(
      input_context, fw_wih, fw_bih, gxfw, 512, 1536, 768, 0, 0);
  gemm128<1><<<dim3(12, 1), blk, 0, stream>>>(
      input_context, bw_wih, bw_bih, gxbw, 1, 1536, 768, 2, 511);
  gemm128<1><<<dim3(24, 8), blk, 0, stream>>>(
      output_context, dec_wih, dec_bih, gxdec, 1024, 3072, 768, 1, 0);
  if (do_bf16)
    wt_transpose<<<dim3(454, 16), blk, 0, stream>>>(W_pred, Wt);

  recur_kernel<<<dim3(NWG), dim3(NT), 0, stream>>>(
      gxfw, gxdec, gxbw, fw_whh, fw_bhh, dec_whh, dec_bhh, bw_bhh,
      fwrep, decrep, dec_hs, dec_hs_bf, do_bf16);

  if (do_bf16)
    gemm_vocab_bf16<<<dim3(227, 8), dim3(512), 0, stream>>>(
        dec_hs_bf, Wt, out);
  else
    gemm128<0><<<dim3(227, 8), blk, 0, stream>>>(
        dec_hs, W_pred, nullptr, out, 1024, NV, 1024, 0, 0);
}

// Round 7
// 7071.249 us; speedup vs baseline: 1.3486x; 1.3486x over previous
//
#include <hip/hip_runtime.h>
#include <math.h>

// ---------------------------------------------------------------------------
// Sizes (fixed by the problem)
//   input_context  [512][768]   output_context [1024][768]
//   fw_wih [1536][768] fw_whh [1536][512] fw_bih/bhh [1536]
//   bw_wih [1536][768] (whh unused: bwd_hs[-1] = one step from h0=0)
//   dec_wih [3072][768] dec_whh [3072][1024] dec_bih/bhh [3072]
//   W_pred [1024][28996]   out [1024][28996] fp32
// ---------------------------------------------------------------------------

typedef unsigned long long u64;
typedef unsigned short ushort_t;
typedef __attribute__((ext_vector_type(8))) short short8;   // 8 bf16 (4 VGPR)
typedef __attribute__((ext_vector_type(4))) float f32x4;

#define NWG 32   // sync participants halved vs R2-R5 (was 64)
#define NT 512
#define NV 28996

__device__ __forceinline__ float sigmoidf_(float x) {
  return 1.0f / (1.0f + __expf(-x));
}
__device__ __forceinline__ float tanhf_(float x) {
  const float xx = fminf(fmaxf(x, -15.0f), 15.0f);
  const float e = __expf(2.0f * xx);
  return (e - 1.0f) / (e + 1.0f);
}
__device__ __forceinline__ ushort_t f2bf(float f) {
  union { float f; unsigned u; } c; c.f = f;
  unsigned u = c.u;
  u += 0x7fffu + ((u >> 16) & 1u);  // RNE
  return (ushort_t)(u >> 16);
}

// (tag, h) fused in one 8-byte word: single relaxed agent-scope atomic store
// publishes value + readiness together. Tags are the sole sync authority.
__device__ __forceinline__ u64 pack_ht(float h, unsigned tag) {
  union { float f; unsigned u; } c; c.f = h;
  return ((u64)tag << 32) | (u64)c.u;
}
__device__ __forceinline__ float pk_h(u64 v) {
  union { unsigned u; float f; } c; c.u = (unsigned)v; return c.f;
}
__device__ __forceinline__ void astore(u64* p, u64 v) {
  __hip_atomic_store(p, v, __ATOMIC_RELAXED, __HIP_MEMORY_SCOPE_AGENT);
}
__device__ __forceinline__ u64 aload(const u64* p) {
  return __hip_atomic_load((u64*)p, __ATOMIC_RELAXED, __HIP_MEMORY_SCOPE_AGENT);
}

// ---------------------------------------------------------------------------
// Persistent recurrence kernel. 32 wgs x 512 threads (R2 protocol, remapped).
// fw: 16 units/wg -> one unit per HALF-WAVE (32 lanes, 16 f32 h-chunk/lane).
// dec: 32 units/wg -> one unit per QUARTER-WAVE (16 lanes, 64 f32/lane).
// Sub-waves of a wave read the SAME h chunk from LDS (broadcast) and differ
// only in weights. Butterfly reduce stays within the sub-wave (xor < width).
// Per step: wave0(/1) polls fused (tag,h) slots (full re-read loop, R2 form),
// stages h into ping-pong LDS; barrier; all waves compute; sub-wave lane 0
// computes gates and publishes with one 8B atomic store (4 adjacent units
// per wave -> 32B burst). Depth-2 ping-pong safety as before: a slot is
// overwritten with tag t+2 only after all wgs published t+1, which required
// their step-t reads of that slot to have completed.
// ---------------------------------------------------------------------------
__global__ __launch_bounds__(NT) void recur_kernel(
    const float* __restrict__ gxfw,    // [512][1536]
    const float* __restrict__ gxdec,   // [1024][3072]
    const float* __restrict__ gxbw,    // [1536]
    const float* __restrict__ whh_fw,  // [1536][512]
    const float* __restrict__ bhh_fw,  // [1536]
    const float* __restrict__ whh_dec, // [3072][1024]
    const float* __restrict__ bhh_dec, // [3072]
    const float* __restrict__ bhh_bw,  // [1536]
    u64* fwbuf,                        // [2][512]  zeroed: (h=0, tag=0)
    u64* decbuf,                       // [2][1024] zeroed
    float* __restrict__ dec_hs,        // [1024][1024] f32 (fallback GEMM)
    ushort_t* __restrict__ dec_hs_bf,  // [1024][1024] bf16 (MFMA GEMM)
    int do_bf16)
{
  __shared__ float Hs[2048];  // ping-pong: fw 2x512 (low half), dec 2x1024
  const int tid = threadIdx.x;
  const int wg = blockIdx.x;
  const int wave = tid >> 6;
  const int lane = tid & 63;

  // backward "encoder" = one GRU cell on input row 511 from h0=0 (gh = bhh).
  // Written to decoder parity-0 slots 512..1023 with tag 512.
  if (wg == 0) {
    const int j = tid;  // NT == 512 == HIDDEN
    const float r = sigmoidf_(gxbw[j] + bhh_bw[j]);
    const float z = sigmoidf_(gxbw[512 + j] + bhh_bw[512 + j]);
    const float n = tanhf_(gxbw[1024 + j] + r * bhh_bw[1024 + j]);
    astore(&decbuf[512 + j], pack_ht((1.0f - z) * n, 512u));
  }

  // ---------------- forward encoder: 512 steps ----------------
  {
    const int sl = lane & 31;        // lane within half-wave
    const int sub = lane >> 5;       // 0/1
    const int u = (wg << 4) + (wave << 1) + sub;  // 0..511
    const float br = bhh_fw[u], bz = bhh_fw[512 + u], bn = bhh_fw[1024 + u];
    f32x4 wr[3][4];  // 3 gates x 16 f32 per lane
#pragma unroll
    for (int g = 0; g < 3; ++g) {
      const float* w = whh_fw + (size_t)(g * 512 + u) * 512 + (sl << 4);
#pragma unroll
      for (int i = 0; i < 4; ++i) wr[g][i] = *(const f32x4*)&w[i << 2];
    }
    for (int t = 0; t < 512; ++t) {
      const u64* src = fwbuf + ((t & 1) << 9);
      float* hs = Hs + ((t & 1) << 9);
      // gx loads issued before poll/barrier (latency hidden under the wait)
      const float* gx = gxfw + (size_t)t * 1536;
      const float g0 = gx[u], g1 = gx[512 + u], g2 = gx[1024 + u];
      if (wave == 0) {  // R2-form full re-read poll + LDS stage
        u64 v[8];
        for (;;) {
          bool ok = true;
#pragma unroll
          for (int j = 0; j < 8; ++j) {
            v[j] = aload(src + (j << 6) + lane);
            ok &= ((unsigned)(v[j] >> 32) >= (unsigned)t);
          }
          if (__all(ok)) break;
        }
#pragma unroll
        for (int j = 0; j < 8; ++j) hs[(j << 6) + lane] = pk_h(v[j]);
      }
      __syncthreads();  // the only barrier per fw step
      f32x4 h4[4];
#pragma unroll
      for (int i = 0; i < 4; ++i)
        h4[i] = *(const f32x4*)&hs[(sl << 4) + (i << 2)];
      float p0 = 0.f, p1 = 0.f, p2 = 0.f;
#pragma unroll
      for (int i = 0; i < 4; ++i) {
        p0 += wr[0][i][0] * h4[i][0] + wr[0][i][1] * h4[i][1] +
              wr[0][i][2] * h4[i][2] + wr[0][i][3] * h4[i][3];
        p1 += wr[1][i][0] * h4[i][0] + wr[1][i][1] * h4[i][1] +
              wr[1][i][2] * h4[i][2] + wr[1][i][3] * h4[i][3];
        p2 += wr[2][i][0] * h4[i][0] + wr[2][i][1] * h4[i][1] +
              wr[2][i][2] * h4[i][2] + wr[2][i][3] * h4[i][3];
      }
#pragma unroll
      for (int s = 1; s < 32; s <<= 1) {  // stays within the half-wave
        p0 += __shfl_xor(p0, s, 64);
        p1 += __shfl_xor(p1, s, 64);
        p2 += __shfl_xor(p2, s, 64);
      }
      if (sl == 0) {  // lanes 0 and 32: gates + publish (8B atomic store)
        const float hold = hs[u];
        const float r = sigmoidf_(g0 + p0 + br);
        const float z = sigmoidf_(g1 + p1 + bz);
        const float n = tanhf_(g2 + r * (p2 + bn));
        const float hnew = (1.0f - z) * n + z * hold;
        u64* dst = (t < 511) ? (fwbuf + (((t + 1) & 1) << 9) + u)
                             : (decbuf + u);  // parity 0, tag 512
        astore(dst, pack_ht(hnew, (unsigned)(t + 1)));
      }
    }
  }
  __syncthreads();  // LDS region handoff fw -> dec

  // ---------------- decoder: 1024 steps ----------------
  {
    const int sl = lane & 15;        // lane within quarter-wave
    const int sub = lane >> 4;       // 0..3
    const int u = (wg << 5) + (wave << 2) + sub;  // 0..1023
    const float bb0 = bhh_dec[u], bb1 = bhh_dec[1024 + u],
                bb2 = bhh_dec[2048 + u];
    for (int td = 0; td < 1024; ++td) {
      const int t = 512 + td;  // global tag
      const u64* src = decbuf + ((t & 1) << 10);
      float* hs = Hs + ((t & 1) << 10);
      const float* gx = gxdec + (size_t)td * 3072;
      const float g0 = gx[u], g1 = gx[1024 + u], g2 = gx[2048 + u];
      if (wave < 2) {  // two polling waves, 8 slot-groups (512 u64) each
        const u64* s2 = src + (wave << 9);
        float* h2 = hs + (wave << 9);
        u64 v[8];
        for (;;) {
          bool ok = true;
#pragma unroll
          for (int j = 0; j < 8; ++j) {
            v[j] = aload(s2 + (j << 6) + lane);
            ok &= ((unsigned)(v[j] >> 32) >= (unsigned)t);
          }
          if (__all(ok)) break;
        }
#pragma unroll
        for (int j = 0; j < 8; ++j) h2[(j << 6) + lane] = pk_h(v[j]);
      }
      __syncthreads();  // the only barrier per dec step
      const float* w0 = whh_dec + (size_t)u * 1024 + (sl << 6);
      const float* w1 = whh_dec + (size_t)(1024 + u) * 1024 + (sl << 6);
      const float* w2 = whh_dec + (size_t)(2048 + u) * 1024 + (sl << 6);
      const float* hp = hs + (sl << 6);
      float p0 = 0.f, p1 = 0.f, p2 = 0.f;
#pragma unroll
      for (int i = 0; i < 16; ++i) {
        const f32x4 hv = *(const f32x4*)&hp[i << 2];
        const f32x4 a = *(const f32x4*)&w0[i << 2];
        const f32x4 b = *(const f32x4*)&w1[i << 2];
        const f32x4 c = *(const f32x4*)&w2[i << 2];
        p0 += a[0] * hv[0] + a[1] * hv[1] + a[2] * hv[2] + a[3] * hv[3];
        p1 += b[0] * hv[0] + b[1] * hv[1] + b[2] * hv[2] + b[3] * hv[3];
        p2 += c[0] * hv[0] + c[1] * hv[1] + c[2] * hv[2] + c[3] * hv[3];
      }
#pragma unroll
      for (int s = 1; s < 16; s <<= 1) {  // stays within the quarter-wave
        p0 += __shfl_xor(p0, s, 64);
        p1 += __shfl_xor(p1, s, 64);
        p2 += __shfl_xor(p2, s, 64);
      }
      if (sl == 0) {  // lanes 0,16,32,48: gates + publish (32B burst/wave)
        const float hold = hs[u];
        const float r = sigmoidf_(g0 + p0 + bb0);
        const float z = sigmoidf_(g1 + p1 + bb1);
        const float n = tanhf_(g2 + r * (p2 + bb2));
        const float hnew = (1.0f - z) * n + z * hold;
        astore(decbuf + (((t + 1) & 1) << 10) + u,
               pack_ht(hnew, (unsigned)(t + 1)));
        if (do_bf16)
          dec_hs_bf[(size_t)td * 1024 + u] = f2bf(hnew);
        else
          dec_hs[(size_t)td * 1024 + u] = hnew;
      }
    }
  }
}

// ---------------------------------------------------------------------------
// W_pred [1024][28996] f32  ->  Wt [28996][1024] bf16 (k-contiguous rows).
// ---------------------------------------------------------------------------
__global__ __launch_bounds__(256) void wt_transpose(
    const float* __restrict__ W, ushort_t* __restrict__ Wt) {
  __shared__ float T[64][65];
  const int tid = threadIdx.x;
  const int n0 = blockIdx.x * 64;
  const int k0 = blockIdx.y * 64;
  const int nloc = tid & 63;
  const int q = tid >> 6;  // 0..3
  const bool nok = (n0 + nloc) < NV;
#pragma unroll
  for (int r = 0; r < 16; ++r) {
    const int kloc = q + r * 4;
    T[kloc][nloc] = nok ? W[(size_t)(k0 + kloc) * NV + n0 + nloc] : 0.f;
  }
  __syncthreads();
  const int kloc2 = tid & 63;
#pragma unroll
  for (int w = 0; w < 16; ++w) {
    const int nloc2 = q + w * 4;
    if (n0 + nloc2 < NV)
      Wt[(size_t)(n0 + nloc2) * 1024 + k0 + kloc2] = f2bf(T[kloc2][nloc2]);
  }
}

// ---------------------------------------------------------------------------
// bf16 MFMA vocab GEMM: out[1024][28996] = dec_hs_bf x Wt^T.
// 128x128 tile, BK=64, 512 threads = 8 waves (4M x 2N), 16x16x32 MFMA.
// ---------------------------------------------------------------------------
__global__ __launch_bounds__(512) void gemm_vocab_bf16(
    const ushort_t* __restrict__ A,   // [1024][1024] bf16
    const ushort_t* __restrict__ Bt,  // [28996][1024] bf16
    float* __restrict__ C) {          // [1024][28996] f32
  __shared__ short As[128 * 72];
  __shared__ short Bs[128 * 72];
  const int tid = threadIdx.x;
  const int lane = tid & 63;
  const int wid = tid >> 6;
  const int wm = wid >> 1;   // 0..3
  const int wn = wid & 1;    // 0..1
  const int n0 = blockIdx.x * 128;
  const int m0 = blockIdx.y * 128;

  const int frow = tid >> 2;          // 0..127 (fill row)
  const int fko = (tid & 3) << 4;     // k offset 0/16/32/48
  const bool bok = (n0 + frow) < NV;
  const uint4 zz = make_uint4(0, 0, 0, 0);

  f32x4 acc[2][4];
#pragma unroll
  for (int i = 0; i < 2; ++i)
#pragma unroll
    for (int j = 0; j < 4; ++j) acc[i][j] = (f32x4){0.f, 0.f, 0.f, 0.f};

  for (int k0 = 0; k0 < 1024; k0 += 64) {
    {  // A fill: 128 rows x 64 k bf16, 32B per thread
      const uint4* s = (const uint4*)(A + (size_t)(m0 + frow) * 1024 + k0 + fko);
      uint4* d = (uint4*)&As[frow * 72 + fko];
      d[0] = s[0];
      d[1] = s[1];
    }
    {  // B fill from Wt rows (n-major, k-contiguous)
      uint4 v0 = zz, v1 = zz;
      if (bok) {
        const uint4* s =
            (const uint4*)(Bt + (size_t)(n0 + frow) * 1024 + k0 + fko);
        v0 = s[0];
        v1 = s[1];
      }
      uint4* d = (uint4*)&Bs[frow * 72 + fko];
      d[0] = v0;
      d[1] = v1;
    }
    __syncthreads();
#pragma unroll
    for (int ks = 0; ks < 64; ks += 32) {
      short8 a[2], b[4];
#pragma unroll
      for (int fm = 0; fm < 2; ++fm)
        a[fm] = *(const short8*)&As[(wm * 32 + fm * 16 + (lane & 15)) * 72 +
                                    ks + ((lane >> 4) << 3)];
#pragma unroll
      for (int fn = 0; fn < 4; ++fn)
        b[fn] = *(const short8*)&Bs[(wn * 64 + fn * 16 + (lane & 15)) * 72 +
                                    ks + ((lane >> 4) << 3)];
#pragma unroll
      for (int fm = 0; fm < 2; ++fm)
#pragma unroll
        for (int fn = 0; fn < 4; ++fn)
          acc[fm][fn] = __builtin_amdgcn_mfma_f32_16x16x32_bf16(
              a[fm], b[fn], acc[fm][fn], 0, 0, 0);
    }
    __syncthreads();
  }

#pragma unroll
  for (int fm = 0; fm < 2; ++fm) {
#pragma unroll
    for (int fn = 0; fn < 4; ++fn) {
      const int col = n0 + wn * 64 + fn * 16 + (lane & 15);
      if (col < NV) {
        const int rbase = m0 + wm * 32 + fm * 16 + ((lane >> 4) << 2);
#pragma unroll
        for (int r = 0; r < 4; ++r)
          C[(size_t)(rbase + r) * NV + col] = acc[fm][fn][r];
      }
    }
  }
}

// ---------------------------------------------------------------------------
// fp32 GEMM, 128x128 tile, BK=16, 256 threads, 8x8 microtile.
//   BT=1: C[M,N] = Amap[M,K] * B[N,K]^T + bias   (input projections)
//   BT=0: C[M,N] = A[M,K]   * B[K,N]   (+bias)   (vocab fallback)
// rowmode: 0 identity, 1 decoder shift (row m -> max(m-1,0)), 2 fixed row.
// ---------------------------------------------------------------------------
#define GBM 128
#define GBN 128
#define GBK 16
#define GLDS 132

template <int BT>
__global__ __launch_bounds__(256) void gemm128(
    const float* __restrict__ A, const float* __restrict__ B,
    const float* __restrict__ bias, float* __restrict__ C, int M, int N, int K,
    int rowmode, int fixedrow) {
  __shared__ float As[GBK][GLDS];
  __shared__ float Bs[GBK][GLDS];
  const int tid = threadIdx.x;
  const int n0 = blockIdx.x * GBN;
  const int m0 = blockIdx.y * GBM;
  const int tx = tid & 15;
  const int ty = tid >> 4;
  float acc[8][8];
#pragma unroll
  for (int i = 0; i < 8; ++i)
#pragma unroll
    for (int j = 0; j < 8; ++j) acc[i][j] = 0.f;

  const int fl = tid >> 1;
  const int fk = (tid & 1) << 3;
  const int am = m0 + fl;
  int asrow = am;
  if (rowmode == 1) asrow = (am == 0) ? 0 : am - 1;
  else if (rowmode == 2) asrow = fixedrow;
  const bool aok = (am < M);
  const bool nfull = (n0 + GBN <= N);

  for (int k0 = 0; k0 < K; k0 += GBK) {
    {
      float4 v0 = make_float4(0.f, 0.f, 0.f, 0.f), v1 = v0;
      if (aok) {
        const float* p = A + (size_t)asrow * K + k0 + fk;
        v0 = *(const float4*)p;
        v1 = *(const float4*)(p + 4);
      }
      As[fk + 0][fl] = v0.x; As[fk + 1][fl] = v0.y;
      As[fk + 2][fl] = v0.z; As[fk + 3][fl] = v0.w;
      As[fk + 4][fl] = v1.x; As[fk + 5][fl] = v1.y;
      As[fk + 6][fl] = v1.z; As[fk + 7][fl] = v1.w;
    }
    if (BT) {
      const int bn = n0 + fl;
      float4 v0 = make_float4(0.f, 0.f, 0.f, 0.f), v1 = v0;
      if (bn < N) {
        const float* p = B + (size_t)bn * K + k0 + fk;
        v0 = *(const float4*)p;
        v1 = *(const float4*)(p + 4);
      }
      Bs[fk + 0][fl] = v0.x; Bs[fk + 1][fl] = v0.y;
      Bs[fk + 2][fl] = v0.z; Bs[fk + 3][fl] = v0.w;
      Bs[fk + 4][fl] = v1.x; Bs[fk + 5][fl] = v1.y;
      Bs[fk + 6][fl] = v1.z; Bs[fk + 7][fl] = v1.w;
    } else {
      const int kl = tid >> 4;
      const int nq = (tid & 15) << 3;
      const float* p = B + (size_t)(k0 + kl) * N + n0 + nq;
      if (nfull) {
        *(float4*)&Bs[kl][nq] = *(const float4*)p;
        *(float4*)&Bs[kl][nq + 4] = *(const float4*)(p + 4);
      } else {
#pragma unroll
        for (int j = 0; j < 8; ++j)
          Bs[kl][nq + j] = (n0 + nq + j < N) ? p[j] : 0.f;
      }
    }
    __syncthreads();
#pragma unroll
    for (int k = 0; k < GBK; ++k) {
      const float4 a0 = *(const float4*)&As[k][ty << 3];
      const float4 a1 = *(const float4*)&As[k][(ty << 3) + 4];
      const float4 b0 = *(const float4*)&Bs[k][tx << 3];
      const float4 b1 = *(const float4*)&Bs[k][(tx << 3) + 4];
      const float av[8] = {a0.x, a0.y, a0.z, a0.w, a1.x, a1.y, a1.z, a1.w};
      const float bv[8] = {b0.x, b0.y, b0.z, b0.w, b1.x, b1.y, b1.z, b1.w};
#pragma unroll
      for (int i = 0; i < 8; ++i)
#pragma unroll
        for (int j = 0; j < 8; ++j) acc[i][j] += av[i] * bv[j];
    }
    __syncthreads();
  }

  const int mb = m0 + (ty << 3);
  const int nb = n0 + (tx << 3);
#pragma unroll
  for (int i = 0; i < 8; ++i) {
    const int m = mb + i;
    if (m >= M) continue;
    float o[8];
#pragma unroll
    for (int j = 0; j < 8; ++j) o[j] = acc[i][j];
    if (nfull) {
      if (bias) {
#pragma unroll
        for (int j = 0; j < 8; ++j) o[j] += bias[nb + j];
      }
      *(float4*)&C[(size_t)m * N + nb] = make_float4(o[0], o[1], o[2], o[3]);
      *(float4*)&C[(size_t)m * N + nb + 4] = make_float4(o[4], o[5], o[6], o[7]);
    } else {
#pragma unroll
      for (int j = 0; j < 8; ++j) {
        const int n = nb + j;
        if (n < N) C[(size_t)m * N + n] = o[j] + (bias ? bias[n] : 0.f);
      }
    }
  }
}

// ---------------------------------------------------------------------------
// Workspace layout (byte offsets):
//   0         fwbuf  u64[1024]        (zeroed each launch)
//   8192      decbuf u64[2048]        (zeroed each launch)
//   24576     gxbw   f32[1536]
//   30720     gxfw   f32[512*1536]
//   3176448   gxdec  f32[1024*3072]
//   15759360  dec_hs f32[1024*1024]  UNION  dec_hs_bf16 u16 (bf16 path)
//   19953664  Wt bf16 u16[28996*1024]  -> end 79337472 (~79.3 MB)
// bf16 path requires ws_size >= 79337472; else fp32 fallback (<20 MB).
// ---------------------------------------------------------------------------
extern "C" void kernel_launch(void* const* d_in, const int* in_sizes, int n_in,
                              void* d_out, int out_size, void* d_ws,
                              size_t ws_size, hipStream_t stream) {
  (void)in_sizes; (void)n_in; (void)out_size;
  const float* input_context  = (const float*)d_in[0];
  const float* output_context = (const float*)d_in[1];
  const float* fw_wih = (const float*)d_in[2];
  const float* fw_whh = (const float*)d_in[3];
  const float* fw_bih = (const float*)d_in[4];
  const float* fw_bhh = (const float*)d_in[5];
  const float* bw_wih = (const float*)d_in[6];
  const float* bw_bih = (const float*)d_in[8];
  const float* bw_bhh = (const float*)d_in[9];
  const float* dec_wih = (const float*)d_in[10];
  const float* dec_whh = (const float*)d_in[11];
  const float* dec_bih = (const float*)d_in[12];
  const float* dec_bhh = (const float*)d_in[13];
  const float* W_pred  = (const float*)d_in[14];
  float* out = (float*)d_out;

  char* wsb = (char*)d_ws;
  u64* fwbuf   = (u64*)wsb;
  u64* decbuf  = (u64*)(wsb + 8192);
  float* gxbw  = (float*)(wsb + 24576);
  float* gxfw  = (float*)(wsb + 30720);
  float* gxdec = (float*)(wsb + 3176448);
  float* dec_hs = (float*)(wsb + 15759360);
  ushort_t* dec_hs_bf = (ushort_t*)(wsb + 15759360);  // union with dec_hs
  ushort_t* Wt = (ushort_t*)(wsb + 19953664);
  const int do_bf16 = (ws_size >= 79337472u) ? 1 : 0;

  // zero the (tag,h) buffers: tag=0 (= ready only for t=0), h0=0
  hipMemsetAsync(d_ws, 0, 24576, stream);

  const dim3 blk(256);
  gemm128<1><<<dim3(12, 4), blk, 0, stream>>>(
      input_context, fw_wih, fw_bih, gxfw, 512, 1536, 768, 0, 0);
  gemm128<1><<<dim3(12, 1), blk, 0, stream>>>(
      input_context, bw_wih, bw_bih, gxbw, 1, 1536, 768, 2, 511);
  gemm128<1><<<dim3(24, 8), blk, 0, stream>>>(
      output_context, dec_wih, dec_bih, gxdec, 1024, 3072, 768, 1, 0);
  if (do_bf16)
    wt_transpose<<<dim3(454, 16), blk, 0, stream>>>(W_pred, Wt);

  recur_kernel<<<dim3(NWG), dim3(NT), 0, stream>>>(
      gxfw, gxdec, gxbw, fw_whh, fw_bhh, dec_whh, dec_bhh, bw_bhh,
      fwbuf, decbuf, dec_hs, dec_hs_bf, do_bf16);

  if (do_bf16)
    gemm_vocab_bf16<<<dim3(227, 8), dim3(512), 0, stream>>>(
        dec_hs_bf, Wt, out);
  else
    gemm128<0><<<dim3(227, 8), blk, 0, stream>>>(
        dec_hs, W_pred, nullptr, out, 1024, NV, 1024, 0, 0);
}